// Round 14
// baseline (83.197 us; speedup 1.0000x reference)
//
#include <hip/hip_runtime.h>
#include <cstdint>
#include <cmath>

// ---------------------------------------------------------------------------
// Threefry-2x32 (JAX/XLA exact): 20 rounds, 5 groups of 4.
// ---------------------------------------------------------------------------
struct U2 { uint32_t a, b; };

__host__ __device__ inline uint32_t rotl32(uint32_t v, int r) {
    return (v << r) | (v >> (32 - r));
}

__host__ __device__ inline U2 tf2x32(U2 k, uint32_t x0, uint32_t x1) {
    uint32_t ks0 = k.a, ks1 = k.b, ks2 = k.a ^ k.b ^ 0x1BD11BDAu;
    x0 += ks0; x1 += ks1;
#define TF_R(r) { x0 += x1; x1 = rotl32(x1, r); x1 ^= x0; }
    TF_R(13) TF_R(15) TF_R(26) TF_R(6)
    x0 += ks1; x1 += ks2 + 1u;
    TF_R(17) TF_R(29) TF_R(16) TF_R(24)
    x0 += ks2; x1 += ks0 + 2u;
    TF_R(13) TF_R(15) TF_R(26) TF_R(6)
    x0 += ks0; x1 += ks1 + 3u;
    TF_R(17) TF_R(29) TF_R(16) TF_R(24)
    x0 += ks1; x1 += ks2 + 4u;
    TF_R(13) TF_R(15) TF_R(26) TF_R(6)
    x0 += ks2; x1 += ks0 + 5u;
#undef TF_R
    U2 r; r.a = x0; r.b = x1; return r;
}

// ---------------------------------------------------------------------------
// JAX uniform/normal building blocks (f32, XLA-exact op ordering)
// ---------------------------------------------------------------------------
__device__ inline float bits_to_u01(uint32_t bits) {
    return __uint_as_float((bits >> 9) | 0x3f800000u) - 1.0f;
}

__device__ inline float erfinv_xla(float x) {
    #pragma clang fp contract(off)
    float w = -log1pf(-(x * x));
    float p;
    if (w < 5.0f) {
        w = w - 2.5f;
        p = 2.81022636e-08f;
        p = 3.43273939e-07f + p * w;
        p = -3.5233877e-06f + p * w;
        p = -4.39150654e-06f + p * w;
        p = 0.00021858087f + p * w;
        p = -0.00125372503f + p * w;
        p = -0.00417768164f + p * w;
        p = 0.246640727f + p * w;
        p = 1.50140941f + p * w;
    } else {
        w = sqrtf(w) - 3.0f;
        p = -0.000200214257f;
        p = 0.000100950558f + p * w;
        p = 0.00134934322f + p * w;
        p = -0.00367342844f + p * w;
        p = 0.00573950773f + p * w;
        p = -0.0076224613f + p * w;
        p = 0.00943887047f + p * w;
        p = 1.00167406f + p * w;
        p = 2.83297682f + p * w;
    }
    return p * x;
}

// EXACT path (Wood/gamma sampler: discrete accept decisions)
__device__ inline float bits_to_normal(uint32_t bits) {
    #pragma clang fp contract(off)
    float f = bits_to_u01(bits);
    const float lo = -0.99999994f;
    float u = f * 2.0f + lo;
    u = fmaxf(lo, u);
    return 1.4142135623730951f * erfinv_xla(u);
}

// FAST path (finalize2's v vector only: continuous propagation, ~1e-6 err)
__device__ inline float bits_to_normal_fast(uint32_t bits) {
    float f = bits_to_u01(bits);
    const float lo = -0.99999994f;
    float x = fmaxf(lo, fmaf(f, 2.0f, lo));
    float w = -__logf(fmaf(-x, x, 1.0f));      // v_log_f32
    float p;
    if (w < 5.0f) {
        w = w - 2.5f;
        p = 2.81022636e-08f;
        p = fmaf(p, w, 3.43273939e-07f);
        p = fmaf(p, w, -3.5233877e-06f);
        p = fmaf(p, w, -4.39150654e-06f);
        p = fmaf(p, w, 0.00021858087f);
        p = fmaf(p, w, -0.00125372503f);
        p = fmaf(p, w, -0.00417768164f);
        p = fmaf(p, w, 0.246640727f);
        p = fmaf(p, w, 1.50140941f);
    } else {
        w = sqrtf(w) - 3.0f;
        p = -0.000200214257f;
        p = fmaf(p, w, 0.000100950558f);
        p = fmaf(p, w, 0.00134934322f);
        p = fmaf(p, w, -0.00367342844f);
        p = fmaf(p, w, 0.00573950773f);
        p = fmaf(p, w, -0.0076224613f);
        p = fmaf(p, w, 0.00943887047f);
        p = fmaf(p, w, 1.00167406f);
        p = fmaf(p, w, 2.83297682f);
    }
    return 1.4142135623730951f * (p * x);
}

__device__ inline float normal_scalar(U2 key) {
    return bits_to_normal(tf2x32(key, 0u, 0u).a);
}

__device__ inline float uniform_scalar(U2 key) {
    uint32_t bits = tf2x32(key, 0u, 0u).a;
    return bits_to_u01(bits);
}

// ---------------------------------------------------------------------------
// Marsaglia-Tsang gamma sampler in log-space (alpha >= 1 path), JAX _gamma_one
// ---------------------------------------------------------------------------
__device__ float gamma_log_one(U2 key, float d, float c) {
    #pragma clang fp contract(off)
    float X = 0.0f, V = 1.0f, U = 2.0f;
    for (;;) {
        float x2 = X * X;
        float sq = 1.0f - 0.0331f * (x2 * x2);
        bool cont;
        if (U < sq) {
            cont = false;
        } else {
            float rhs = X * (0.5f * X) + d * ((1.0f - V) + logf(V));
            cont = (logf(U) >= rhs);
        }
        if (!cont) break;

        U2 t03 = tf2x32(key, 0u, 3u);
        U2 t14 = tf2x32(key, 1u, 4u);
        U2 t25 = tf2x32(key, 2u, 5u);
        U2 nkey; nkey.a = t03.a; nkey.b = t14.a;
        U2 xkey; xkey.a = t25.a; xkey.b = t03.b;
        U2 Ukey; Ukey.a = t14.b; Ukey.b = t25.b;
        key = nkey;

        float x, v;
        do {
            U2 s02 = tf2x32(xkey, 0u, 2u);
            U2 s13 = tf2x32(xkey, 1u, 3u);
            U2 sub; sub.a = s02.b; sub.b = s13.b;
            xkey.a = s02.a; xkey.b = s13.a;
            x = normal_scalar(sub);
            v = 1.0f + c * x;
        } while (v <= 0.0f);
        X = x;
        V = (v * v) * v;
        U = uniform_scalar(Ukey);
    }
    return logf(d) + logf(V);
}

// ---------------------------------------------------------------------------
// f32 -> bf16 (round-nearest-even), finite inputs
// ---------------------------------------------------------------------------
__device__ inline unsigned short f2bf(float f) {
    uint32_t u = __float_as_uint(f);
    uint32_t r = (u + 0x7FFFu + ((u >> 16) & 1u)) >> 16;
    return (unsigned short)r;
}

__device__ inline uint32_t pkbf2(float a, float b) {
    return (uint32_t)f2bf(a) | ((uint32_t)f2bf(b) << 16);
}

// ---------------------------------------------------------------------------
// Wood's rejection sampler, ROUND-PARALLEL (4 lanes/element, bit-exact)
// ---------------------------------------------------------------------------
__device__ void wood_w_par(int e, U2 key_a, U2 key_b, U2 ku, float xxf,
                           float ccf, float Ap, float Bm, float d, float c,
                           float* __restrict__ w_out) {
    #pragma clang fp contract(off)
    const int lane = threadIdx.x & 63;
    const int s = lane & 3;
    const int gbase = lane & ~3;
    float w0 = 0.0f, w_sel = 0.0f;
    bool done = false;
    for (int base = 0; base < 64 && !done; base += 4) {
        const int r = base + s;
        uint32_t j = (uint32_t)r * 16384u + (uint32_t)e;
        uint32_t m0 = 2u * j, m1 = 2u * j + 1u;
        U2 ka, kb;
        if (m1 < 1048576u) {
            ka.a = tf2x32(key_a, m0, m0 + 1048576u).a;
            ka.b = tf2x32(key_a, m1, m1 + 1048576u).a;
            kb.a = tf2x32(key_b, m0, m0 + 1048576u).a;
            kb.b = tf2x32(key_b, m1, m1 + 1048576u).a;
        } else {
            ka.a = tf2x32(key_a, m0 - 1048576u, m0).b;
            ka.b = tf2x32(key_a, m1 - 1048576u, m1).b;
            kb.a = tf2x32(key_b, m0 - 1048576u, m0).b;
            kb.b = tf2x32(key_b, m1 - 1048576u, m1).b;
        }
        float lga = gamma_log_one(ka, d, c);
        float lgb = gamma_log_one(kb, d, c);
        float mx = fmaxf(lga, lgb);
        float ga = expf(lga - mx), gb = expf(lgb - mx);
        float z = ga / (ga + gb);
        uint32_t ub = (j < 524288u) ? tf2x32(ku, j, j + 524288u).a
                                    : tf2x32(ku, j - 524288u, j).b;
        float u = bits_to_u01(ub);
        float w = (1.0f - Ap * z) / (1.0f - Bm * z);
        float lhs = (80.0f * w + 511.0f * logf(1.0f - xxf * w)) - ccf;
        bool acc = lhs >= logf(u);
        if (base == 0) w0 = __shfl(w, gbase, 64);
        unsigned long long m = __ballot(acc);
        unsigned nib = (unsigned)((m >> gbase) & 0xFull);
        if (nib) {
            int first = __ffs((int)nib) - 1;
            w_sel = __shfl(w, gbase + first, 64);
            done = true;
        }
    }
    if (!done) w_sel = w0;
    if (s == 0) w_out[e] = w_sel;
}

// ---------------------------------------------------------------------------
// prep3 (Path A): wood-parallel + convert_a (LINEAR) + transpose_w + kld.
//   blocks [0,256)     : Wood's w, round-parallel (64 elems/block)
//   blocks [256,4352)  : A f32 -> LINEAR bf16 (register-direct gemm A path)
//   blocks [4352,4480) : W transpose -> swizzled bf16 Wt (p = g ^ (n&7))
//   block  4480        : kld copy
// ---------------------------------------------------------------------------
__global__ __launch_bounds__(256) void prep3(
    const float* __restrict__ A, unsigned short* __restrict__ Ab,
    const float* __restrict__ Wm, unsigned short* __restrict__ Wt,
    const float* __restrict__ kld, float* __restrict__ kldo,
    U2 key_a, U2 key_b, U2 ku, float xxf, float ccf, float Ap, float Bm,
    float d, float c, float* __restrict__ wbuf) {
    __shared__ float t[64][65];
    const int b = blockIdx.x;
    if (b < 256) {
        const int wavid = threadIdx.x >> 6;
        const int e = b * 64 + wavid * 16 + ((threadIdx.x & 63) >> 2);
        wood_w_par(e, key_a, key_b, ku, xxf, ccf, Ap, Bm, d, c, wbuf);
    } else if (b < 4352) {
        const int row = (b - 256) * 4 + (threadIdx.x >> 6);
        const int lane = threadIdx.x & 63;
        const float* src = A + (size_t)row * 1024;
        unsigned short* dst = Ab + (size_t)row * 1024;
        #pragma unroll
        for (int q = 0; q < 4; ++q) {
            const int k0 = q * 256 + lane * 4;
            float4 v = *(const float4*)(src + k0);
            ushort4 w;
            w.x = f2bf(v.x); w.y = f2bf(v.y); w.z = f2bf(v.z); w.w = f2bf(v.w);
            *(ushort4*)(dst + k0) = w;                 // linear layout
        }
    } else if (b < 4480) {
        const int tb = b - 4352;
        const int kb = tb & 15;
        const int nb = tb >> 4;
        const int tx = threadIdx.x & 63;
        const int ty = threadIdx.x >> 6;
        #pragma unroll
        for (int i = 0; i < 64; i += 4)
            t[i + ty][tx] = Wm[(size_t)(kb * 64 + i + ty) * 512 + nb * 64 + tx];
        __syncthreads();
        const int g = tx >> 3, e2 = tx & 7;
        #pragma unroll
        for (int i = 0; i < 64; i += 4) {
            int n = i + ty;
            int nglob = nb * 64 + n;
            int p = g ^ (nglob & 7);
            Wt[(size_t)nglob * 1024 + kb * 64 + p * 8 + e2] = f2bf(t[tx][n]);
        }
    } else {
        if (threadIdx.x == 0) kldo[0] = kld[0];
    }
}

// ---------------------------------------------------------------------------
// GEMM (Path A): A register-direct (2-deep asm-load prefetch), B-only LDS DMA.
// BM=128 BN=128 BK=64, 256 thr / 4 waves (2x2), wave tile 64x64 (4x4 frags).
// Per kt region = {8 A global_load_dwordx4 + 4 B gll16}(kt+2) -> vmcnt(12)
// guarantees generation kt+1 complete. LDS = 32KB (B dbuf only).
// ---------------------------------------------------------------------------
typedef __attribute__((ext_vector_type(8))) short bf16x8;
typedef __attribute__((ext_vector_type(4))) float f32x4;
typedef __attribute__((ext_vector_type(4))) unsigned int u32x4;

__device__ inline void gll16(const void* g, void* l) {
    __builtin_amdgcn_global_load_lds(
        (const __attribute__((address_space(1))) void*)g,
        (__attribute__((address_space(3))) void*)l, 16, 0, 0);
}

__global__ __launch_bounds__(256) void gemm_rdma(
    const unsigned short* __restrict__ Ab, const unsigned short* __restrict__ Wt,
    const float* __restrict__ bias, float* __restrict__ out) {
    __shared__ __align__(16) unsigned short Bsm[2][8192];
    const int tid = threadIdx.x;
    const int b = blockIdx.x;
    const int swz = (b & 7) * 64 + (b >> 3);     // XCD-chunked, bijective
    const int bm = swz >> 2;
    const int bn = swz & 3;
    const int wave = tid >> 6, lane = tid & 63;
    const int wm = wave >> 1, wn = wave & 1;
    const int lr = lane & 15, lg = lane >> 4;

    f32x4 acc[4][4] = {};
    u32x4 a0[8], a1[8];         // A banks: [mi*2+ks], 8 bf16 each

    const char* aptr[4];
    #pragma unroll
    for (int mi = 0; mi < 4; ++mi)
        aptr[mi] = (const char*)Ab +
            (size_t)(bm * 128 + wm * 64 + mi * 16 + lr) * 2048 + lg * 16;

    const char* bBase = (const char*)Wt +
        (size_t)(bn * 128 + wave * 32 + (lane >> 3)) * 2048 + (lane & 7) * 16;

#define LOADA(bank, ktv)                                                    \
    {                                                                       \
        _Pragma("unroll")                                                   \
        for (int mi = 0; mi < 4; ++mi)                                      \
            _Pragma("unroll")                                               \
            for (int ks = 0; ks < 2; ++ks)                                  \
                asm volatile("global_load_dwordx4 %0, %1, off"              \
                             : "=v"(bank[mi * 2 + ks])                      \
                             : "v"(aptr[mi] + (ktv) * 128 + ks * 64));      \
    }

#define STAGEB(ktv, buf)                                                    \
    {                                                                       \
        _Pragma("unroll")                                                   \
        for (int ii = 0; ii < 4; ++ii) {                                    \
            const int chunk = wave * 4 + ii;                                \
            gll16(bBase + (size_t)ii * 8 * 2048 + (ktv) * 128,              \
                  (void*)&Bsm[buf][chunk * 512]);                           \
        }                                                                   \
    }

#define BODY(bank, buf, ktv)                                                \
    {                                                                       \
        _Pragma("unroll")                                                   \
        for (int ks = 0; ks < 2; ++ks) {                                    \
            bf16x8 bfr[4];                                                  \
            _Pragma("unroll")                                               \
            for (int ni = 0; ni < 4; ++ni) {                                \
                const int r = wn * 64 + ni * 16 + lr;                       \
                const int p = (ks * 4 + lg) ^ (r & 7);                      \
                bfr[ni] = *(const bf16x8*)&Bsm[buf][r * 64 + p * 8];        \
            }                                                               \
            _Pragma("unroll")                                               \
            for (int mi = 0; mi < 4; ++mi) {                                \
                bf16x8 afv = __builtin_bit_cast(bf16x8, bank[mi * 2 + ks]); \
                _Pragma("unroll")                                           \
                for (int ni = 0; ni < 4; ++ni)                              \
                    acc[mi][ni] = __builtin_amdgcn_mfma_f32_16x16x32_bf16(  \
                        afv, bfr[ni], acc[mi][ni], 0, 0, 0);                \
            }                                                               \
        }                                                                   \
        __builtin_amdgcn_sched_barrier(0);                                  \
        __builtin_amdgcn_s_barrier();                                       \
        if ((ktv) + 2 < 16) {                                               \
            LOADA(bank, (ktv) + 2);                                         \
            STAGEB((ktv) + 2, buf);                                         \
            asm volatile("s_waitcnt vmcnt(12)" ::: "memory");               \
        } else {                                                            \
            asm volatile("s_waitcnt vmcnt(0)" ::: "memory");                \
        }                                                                   \
        __builtin_amdgcn_s_barrier();                                       \
        __builtin_amdgcn_sched_barrier(0);                                  \
    }

    // prologue: generation 0 then generation 1 (fenced so vmcnt order is exact)
    LOADA(a0, 0);
    STAGEB(0, 0);
    __builtin_amdgcn_sched_barrier(0);
    LOADA(a1, 1);
    STAGEB(1, 1);
    asm volatile("s_waitcnt vmcnt(12)" ::: "memory");
    __builtin_amdgcn_s_barrier();
    __builtin_amdgcn_sched_barrier(0);

    for (int ktt = 0; ktt < 16; ktt += 2) {
        BODY(a0, 0, ktt);
        BODY(a1, 1, ktt + 1);
    }
#undef BODY
#undef STAGEB
#undef LOADA

    #pragma unroll
    for (int mi = 0; mi < 4; ++mi) {
        #pragma unroll
        for (int ni = 0; ni < 4; ++ni) {
            const int col = bn * 128 + wn * 64 + ni * 16 + lr;
            const float bcol = bias[col];
            #pragma unroll
            for (int r = 0; r < 4; ++r) {
                const int row = bm * 128 + wm * 64 + mi * 16 + lg * 4 + r;
                float x = acc[mi][ni][r] + bcol;
                float sp = fmaxf(x, 0.0f) + __logf(1.0f + __expf(-fabsf(x)));
                out[(size_t)row * 512 + col] = sp;
            }
        }
    }
}

// ---------------------------------------------------------------------------
// Path B fallback kernels (unchanged)
// ---------------------------------------------------------------------------
__device__ void wood_w_one(int i, U2 key_a, U2 key_b, U2 ku, float xxf,
                           float ccf, float Ap, float Bm, float d, float c,
                           float* __restrict__ w_out) {
    #pragma clang fp contract(off)
    float w_sel = 0.0f, w0 = 0.0f;
    bool found = false;
    for (int r = 0; r < 64 && !found; ++r) {
        uint32_t j = (uint32_t)r * 16384u + (uint32_t)i;
        uint32_t m0 = 2u * j, m1 = 2u * j + 1u;
        U2 ka, kb;
        if (m1 < 1048576u) {
            ka.a = tf2x32(key_a, m0, m0 + 1048576u).a;
            ka.b = tf2x32(key_a, m1, m1 + 1048576u).a;
            kb.a = tf2x32(key_b, m0, m0 + 1048576u).a;
            kb.b = tf2x32(key_b, m1, m1 + 1048576u).a;
        } else {
            ka.a = tf2x32(key_a, m0 - 1048576u, m0).b;
            ka.b = tf2x32(key_a, m1 - 1048576u, m1).b;
            kb.a = tf2x32(key_b, m0 - 1048576u, m0).b;
            kb.b = tf2x32(key_b, m1 - 1048576u, m1).b;
        }
        float lga = gamma_log_one(ka, d, c);
        float lgb = gamma_log_one(kb, d, c);
        float mx = fmaxf(lga, lgb);
        float ga = expf(lga - mx), gb = expf(lgb - mx);
        float z = ga / (ga + gb);
        uint32_t ub = (j < 524288u) ? tf2x32(ku, j, j + 524288u).a
                                    : tf2x32(ku, j - 524288u, j).b;
        float u = bits_to_u01(ub);
        float w = (1.0f - Ap * z) / (1.0f - Bm * z);
        float lhs = (80.0f * w + 511.0f * logf(1.0f - xxf * w)) - ccf;
        bool acc = lhs >= logf(u);
        if (r == 0) w0 = w;
        if (acc) { w_sel = w; found = true; }
    }
    w_out[i] = found ? w_sel : w0;
}

__global__ __launch_bounds__(256) void transpose_w(
    const float* __restrict__ Wm, unsigned short* __restrict__ Wt) {
    __shared__ float t[64][65];
    const int kb = blockIdx.x;
    const int nb = blockIdx.y;
    const int tx = threadIdx.x & 63;
    const int ty = threadIdx.x >> 6;
    #pragma unroll
    for (int i = 0; i < 64; i += 4)
        t[i + ty][tx] = Wm[(size_t)(kb * 64 + i + ty) * 512 + nb * 64 + tx];
    __syncthreads();
    const int g = tx >> 3, e = tx & 7;
    #pragma unroll
    for (int i = 0; i < 64; i += 4) {
        int n = i + ty;
        int nglob = nb * 64 + n;
        int p = g ^ (nglob & 7);
        Wt[(size_t)nglob * 1024 + kb * 64 + p * 8 + e] = f2bf(t[tx][n]);
    }
}

__global__ __launch_bounds__(256) void gemm_bf16(
    const float* __restrict__ A, const unsigned short* __restrict__ Wt,
    const float* __restrict__ bias, float* __restrict__ out) {
    __shared__ __align__(16) unsigned short Asm[128 * 64];
    __shared__ __align__(16) unsigned short Bsm[128 * 64];
    const int tid = threadIdx.x;
    const int b = blockIdx.x;
    const int swz = (b & 7) * 64 + (b >> 3);
    const int bm = swz >> 2;
    const int bn = swz & 3;
    const int wave = tid >> 6, lane = tid & 63;
    const int wm = wave >> 1, wn = wave & 1;
    const int lr = lane & 15, lg = lane >> 4;

    f32x4 acc[4][4] = {};

    const int ar = tid >> 1;
    const int ah = tid & 1;
    const float* Ap = A + (size_t)(bm * 128 + ar) * 1024 + ah * 32;
    const int arx = ar & 7;

    const char* WtB = (const char*)Wt;
    const int brow = bn * 128 + (wave * 4) * 8 + (lane >> 3);
    const int bposb = (lane & 7) * 16;

    for (int kt = 0; kt < 16; ++kt) {
        #pragma unroll
        for (int ii = 0; ii < 4; ++ii) {
            const int chunk = wave * 4 + ii;
            const void* src = WtB + (size_t)(brow + ii * 8) * 2048 + kt * 128 + bposb;
            gll16(src, (void*)&Bsm[chunk * 512]);
        }
        const float* srcA = Ap + kt * 64;
        #pragma unroll
        for (int st = 0; st < 4; ++st) {
            float4 y0 = *(const float4*)(srcA + st * 8);
            float4 y1 = *(const float4*)(srcA + st * 8 + 4);
            uint4 uv;
            uv.x = pkbf2(y0.x, y0.y);
            uv.y = pkbf2(y0.z, y0.w);
            uv.z = pkbf2(y1.x, y1.y);
            uv.w = pkbf2(y1.z, y1.w);
            const int gblk = ah * 4 + st;
            const int p = gblk ^ arx;
            *(uint4*)&Asm[ar * 64 + p * 8] = uv;
        }
        __syncthreads();

        #pragma unroll
        for (int ks = 0; ks < 2; ++ks) {
            bf16x8 af[4], bfr[4];
            #pragma unroll
            for (int mi = 0; mi < 4; ++mi) {
                const int r = wm * 64 + mi * 16 + lr;
                const int p = (ks * 4 + lg) ^ (r & 7);
                af[mi] = *(const bf16x8*)&Asm[r * 64 + p * 8];
            }
            #pragma unroll
            for (int ni = 0; ni < 4; ++ni) {
                const int r = wn * 64 + ni * 16 + lr;
                const int p = (ks * 4 + lg) ^ (r & 7);
                bfr[ni] = *(const bf16x8*)&Bsm[r * 64 + p * 8];
            }
            #pragma unroll
            for (int mi = 0; mi < 4; ++mi)
                #pragma unroll
                for (int ni = 0; ni < 4; ++ni)
                    acc[mi][ni] = __builtin_amdgcn_mfma_f32_16x16x32_bf16(
                        af[mi], bfr[ni], acc[mi][ni], 0, 0, 0);
        }
        __syncthreads();
    }

    #pragma unroll
    for (int mi = 0; mi < 4; ++mi) {
        #pragma unroll
        for (int ni = 0; ni < 4; ++ni) {
            const int col = bn * 128 + wn * 64 + ni * 16 + lr;
            const float bcol = bias[col];
            #pragma unroll
            for (int r = 0; r < 4; ++r) {
                const int row = bm * 128 + wm * 64 + mi * 16 + lg * 4 + r;
                float x = acc[mi][ni][r] + bcol;
                float sp = fmaxf(x, 0.0f) + log1pf(expf(-fabsf(x)));
                out[(size_t)row * 512 + col] = sp;
            }
        }
    }
}

__global__ __launch_bounds__(64) void compute_w_kernel(
    U2 key_a, U2 key_b, U2 ku, float xxf, float ccf, float Ap, float Bm,
    float d, float c, float* __restrict__ w_out) {
    const int i = blockIdx.x * blockDim.x + threadIdx.x;
    if (i >= 16384) return;
    wood_w_one(i, key_a, key_b, ku, xxf, ccf, Ap, Bm, d, c, w_out);
}

__global__ void copy_kld(const float* __restrict__ kld, float* __restrict__ dst) {
    if (blockIdx.x == 0 && threadIdx.x == 0) dst[0] = kld[0];
}

// ---------------------------------------------------------------------------
// finalize2: barrier-free, row-pair (r, r+8192) per wave, halved threefry,
// fast-normal path for v (continuous propagation only).
// ---------------------------------------------------------------------------
__device__ inline float wave_allreduce(float s) {
    #pragma unroll
    for (int off = 1; off < 64; off <<= 1) s += __shfl_xor(s, off);
    return s;
}

__global__ __launch_bounds__(256) void finalize2(
    const float* muraw, float* muout, float* __restrict__ rn,
    const float* __restrict__ wv, U2 kv, float* smp) {
    const int p = blockIdx.x * 4 + (threadIdx.x >> 6);   // row pair 0..8191
    const int lane = threadIdx.x & 63;
    const int r0 = p, r1 = p + 8192;
    const float* q0 = muraw + (size_t)r0 * 512;
    const float* q1 = muraw + (size_t)r1 * 512;

    float m0[8], m1[8];
    {
        float4 t0 = *(const float4*)(q0 + lane * 4);
        float4 t1 = *(const float4*)(q0 + 256 + lane * 4);
        m0[0] = t0.x; m0[1] = t0.y; m0[2] = t0.z; m0[3] = t0.w;
        m0[4] = t1.x; m0[5] = t1.y; m0[6] = t1.z; m0[7] = t1.w;
        float4 t2 = *(const float4*)(q1 + lane * 4);
        float4 t3 = *(const float4*)(q1 + 256 + lane * 4);
        m1[0] = t2.x; m1[1] = t2.y; m1[2] = t2.z; m1[3] = t2.w;
        m1[4] = t3.x; m1[5] = t3.y; m1[6] = t3.z; m1[7] = t3.w;
    }

    float ss0 = 0.0f, ss1 = 0.0f;
    #pragma unroll
    for (int j = 0; j < 8; ++j) { ss0 += m0[j] * m0[j]; ss1 += m1[j] * m1[j]; }
    float n0 = sqrtf(wave_allreduce(ss0));
    float n1 = sqrtf(wave_allreduce(ss1));
    if (lane == 0) {
        float d0 = n0 - 1.0f, d1 = n1 - 1.0f;
        rn[r0] = d0 * d0;
        rn[r1] = d1 * d1;
    }
    float in0 = 1.0f / n0, in1 = 1.0f / n1;
    #pragma unroll
    for (int j = 0; j < 8; ++j) { m0[j] *= in0; m1[j] *= in1; }

    float v0[8], v1[8];
    #pragma unroll
    for (int j = 0; j < 8; ++j) {
        const int c = (j < 4) ? (lane * 4 + j) : (256 + lane * 4 + (j - 4));
        uint32_t idx = (uint32_t)p * 512u + (uint32_t)c;
        U2 h = tf2x32(kv, idx, idx + 4194304u);
        v0[j] = bits_to_normal_fast(h.a);
        v1[j] = bits_to_normal_fast(h.b);
    }

    float p0 = 0.0f, p1 = 0.0f;
    #pragma unroll
    for (int j = 0; j < 8; ++j) { p0 += m0[j] * v0[j]; p1 += m1[j] * v1[j]; }
    p0 = wave_allreduce(p0);
    p1 = wave_allreduce(p1);

    float o0[8], o1[8];
    float s0 = 0.0f, s1 = 0.0f;
    #pragma unroll
    for (int j = 0; j < 8; ++j) {
        o0[j] = v0[j] - m0[j] * p0; s0 += o0[j] * o0[j];
        o1[j] = v1[j] - m1[j] * p1; s1 += o1[j] * o1[j];
    }
    float f0, f1, w0, w1;
    {
        float on0 = sqrtf(wave_allreduce(s0));
        float on1 = sqrtf(wave_allreduce(s1));
        w0 = wv[r0]; w1 = wv[r1];
        f0 = sqrtf(1.0f - w0 * w0) / on0;
        f1 = sqrtf(1.0f - w1 * w1) / on1;
    }

    float* pm0 = muout + (size_t)r0 * 512;
    float* pm1 = muout + (size_t)r1 * 512;
    float* op0 = smp + (size_t)r0 * 512;
    float* op1 = smp + (size_t)r1 * 512;
    float4 wvec;
    wvec.x = o0[0] * f0 + m0[0] * w0; wvec.y = o0[1] * f0 + m0[1] * w0;
    wvec.z = o0[2] * f0 + m0[2] * w0; wvec.w = o0[3] * f0 + m0[3] * w0;
    *(float4*)(op0 + lane * 4) = wvec;
    wvec.x = o0[4] * f0 + m0[4] * w0; wvec.y = o0[5] * f0 + m0[5] * w0;
    wvec.z = o0[6] * f0 + m0[6] * w0; wvec.w = o0[7] * f0 + m0[7] * w0;
    *(float4*)(op0 + 256 + lane * 4) = wvec;
    wvec.x = o1[0] * f1 + m1[0] * w1; wvec.y = o1[1] * f1 + m1[1] * w1;
    wvec.z = o1[2] * f1 + m1[2] * w1; wvec.w = o1[3] * f1 + m1[3] * w1;
    *(float4*)(op1 + lane * 4) = wvec;
    wvec.x = o1[4] * f1 + m1[4] * w1; wvec.y = o1[5] * f1 + m1[5] * w1;
    wvec.z = o1[6] * f1 + m1[6] * w1; wvec.w = o1[7] * f1 + m1[7] * w1;
    *(float4*)(op1 + 256 + lane * 4) = wvec;

    wvec.x = m0[0]; wvec.y = m0[1]; wvec.z = m0[2]; wvec.w = m0[3];
    *(float4*)(pm0 + lane * 4) = wvec;
    wvec.x = m0[4]; wvec.y = m0[5]; wvec.z = m0[6]; wvec.w = m0[7];
    *(float4*)(pm0 + 256 + lane * 4) = wvec;
    wvec.x = m1[0]; wvec.y = m1[1]; wvec.z = m1[2]; wvec.w = m1[3];
    *(float4*)(pm1 + lane * 4) = wvec;
    wvec.x = m1[4]; wvec.y = m1[5]; wvec.z = m1[6]; wvec.w = m1[7];
    *(float4*)(pm1 + 256 + lane * 4) = wvec;
}

// ---------------------------------------------------------------------------
extern "C" void kernel_launch(void* const* d_in, const int* in_sizes, int n_in,
                              void* d_out, int out_size, void* d_ws, size_t ws_size,
                              hipStream_t stream) {
    const float* A    = (const float*)d_in[0];   // [16384,1024]
    const float* Wm   = (const float*)d_in[1];   // [1024,512]
    const float* bias = (const float*)d_in[2];   // [512]
    const float* kld  = (const float*)d_in[3];   // [1]

    float* out = (float*)d_out;
    float* mu   = out;                       // 16384*512
    float* rn   = out + 8388608;             // 16384
    float* kldo = out + 8388608 + 16384;     // 1
    float* smp  = kldo + 1;                  // 16384*512
    float* wbuf = (float*)d_ws;              // 16384 floats scratch

    // ---- host-side key derivation (JAX threefry), key = jax.random.key(42)
    U2 root; root.a = 0u; root.b = 42u;
    U2 t02 = tf2x32(root, 0u, 2u), t13 = tf2x32(root, 1u, 3u);
    U2 kw; kw.a = t02.a; kw.b = t13.a;
    U2 kv; kv.a = t02.b; kv.b = t13.b;
    U2 s02 = tf2x32(kw, 0u, 2u), s13 = tf2x32(kw, 1u, 3u);
    U2 kz; kz.a = s02.a; kz.b = s13.a;
    U2 ku; ku.a = s02.b; ku.b = s13.b;
    U2 b02 = tf2x32(kz, 0u, 2u), b13 = tf2x32(kz, 1u, 3u);
    U2 key_a; key_a.a = b02.a; key_a.b = b13.a;
    U2 key_b; key_b.a = b02.b; key_b.b = b13.b;

    // ---- Wood's sampler constants
    const double kappa = 80.0, dim = 511.0;
    double bb = dim / (sqrt(4.0 * kappa * kappa + dim * dim) + 2.0 * kappa);
    double xxd = (1.0 - bb) / (1.0 + bb);
    double ccd = kappa * xxd + dim * log(1.0 - xxd * xxd);
    float xxf = (float)xxd, ccf = (float)ccd;
    float Apc = (float)(1.0 + bb), Bmc = (float)(1.0 - bb);
    float one3 = 1.0f / 3.0f;
    float dml = 255.5f - one3;
    float cml = one3 / sqrtf(dml);

    const bool bigws = ws_size >= (size_t)(65536 + 1048576);
    if (bigws) {
        unsigned short* Ab = (unsigned short*)d_out;
        unsigned short* Wt = (unsigned short*)((char*)d_ws + 65536);
        float* muraw = smp;
        prep3<<<4481, 256, 0, stream>>>(A, Ab, Wm, Wt, kld, kldo,
                                        key_a, key_b, ku, xxf, ccf, Apc, Bmc,
                                        dml, cml, wbuf);
        gemm_rdma<<<512, 256, 0, stream>>>(Ab, Wt, bias, muraw);
        finalize2<<<2048, 256, 0, stream>>>(muraw, mu, rn, wbuf, kv, smp);
    } else {
        unsigned short* Wt = (unsigned short*)((char*)d_out + 33619984);
        compute_w_kernel<<<256, 64, 0, stream>>>(key_a, key_b, ku, xxf, ccf,
                                                 Apc, Bmc, dml, cml, wbuf);
        transpose_w<<<dim3(16, 8), 256, 0, stream>>>(Wm, Wt);
        gemm_bf16<<<512, 256, 0, stream>>>(A, Wt, bias, mu);
        finalize2<<<2048, 256, 0, stream>>>(mu, mu, rn, wbuf, kv, smp);
        copy_kld<<<1, 64, 0, stream>>>(kld, kldo);
    }
}

// Round 15
// 68.726 us; speedup vs baseline: 1.2106x; 1.2106x over previous
//
#include <hip/hip_runtime.h>
#include <cstdint>
#include <cmath>

// ---------------------------------------------------------------------------
// Threefry-2x32 (JAX/XLA exact): 20 rounds, 5 groups of 4.
// ---------------------------------------------------------------------------
struct U2 { uint32_t a, b; };

__host__ __device__ inline uint32_t rotl32(uint32_t v, int r) {
    return (v << r) | (v >> (32 - r));
}

__host__ __device__ inline U2 tf2x32(U2 k, uint32_t x0, uint32_t x1) {
    uint32_t ks0 = k.a, ks1 = k.b, ks2 = k.a ^ k.b ^ 0x1BD11BDAu;
    x0 += ks0; x1 += ks1;
#define TF_R(r) { x0 += x1; x1 = rotl32(x1, r); x1 ^= x0; }
    TF_R(13) TF_R(15) TF_R(26) TF_R(6)
    x0 += ks1; x1 += ks2 + 1u;
    TF_R(17) TF_R(29) TF_R(16) TF_R(24)
    x0 += ks2; x1 += ks0 + 2u;
    TF_R(13) TF_R(15) TF_R(26) TF_R(6)
    x0 += ks0; x1 += ks1 + 3u;
    TF_R(17) TF_R(29) TF_R(16) TF_R(24)
    x0 += ks1; x1 += ks2 + 4u;
    TF_R(13) TF_R(15) TF_R(26) TF_R(6)
    x0 += ks2; x1 += ks0 + 5u;
#undef TF_R
    U2 r; r.a = x0; r.b = x1; return r;
}

// ---------------------------------------------------------------------------
// JAX uniform/normal building blocks (f32, XLA-exact op ordering)
// ---------------------------------------------------------------------------
__device__ inline float bits_to_u01(uint32_t bits) {
    return __uint_as_float((bits >> 9) | 0x3f800000u) - 1.0f;
}

__device__ inline float erfinv_xla(float x) {
    #pragma clang fp contract(off)
    float w = -log1pf(-(x * x));
    float p;
    if (w < 5.0f) {
        w = w - 2.5f;
        p = 2.81022636e-08f;
        p = 3.43273939e-07f + p * w;
        p = -3.5233877e-06f + p * w;
        p = -4.39150654e-06f + p * w;
        p = 0.00021858087f + p * w;
        p = -0.00125372503f + p * w;
        p = -0.00417768164f + p * w;
        p = 0.246640727f + p * w;
        p = 1.50140941f + p * w;
    } else {
        w = sqrtf(w) - 3.0f;
        p = -0.000200214257f;
        p = 0.000100950558f + p * w;
        p = 0.00134934322f + p * w;
        p = -0.00367342844f + p * w;
        p = 0.00573950773f + p * w;
        p = -0.0076224613f + p * w;
        p = 0.00943887047f + p * w;
        p = 1.00167406f + p * w;
        p = 2.83297682f + p * w;
    }
    return p * x;
}

// EXACT path (Wood/gamma sampler: discrete accept decisions)
__device__ inline float bits_to_normal(uint32_t bits) {
    #pragma clang fp contract(off)
    float f = bits_to_u01(bits);
    const float lo = -0.99999994f;
    float u = f * 2.0f + lo;
    u = fmaxf(lo, u);
    return 1.4142135623730951f * erfinv_xla(u);
}

// FAST path (finalize2's v vector only: continuous propagation, ~1e-6 err)
__device__ inline float bits_to_normal_fast(uint32_t bits) {
    float f = bits_to_u01(bits);
    const float lo = -0.99999994f;
    float x = fmaxf(lo, fmaf(f, 2.0f, lo));
    float w = -__logf(fmaf(-x, x, 1.0f));      // v_log_f32
    float p;
    if (w < 5.0f) {
        w = w - 2.5f;
        p = 2.81022636e-08f;
        p = fmaf(p, w, 3.43273939e-07f);
        p = fmaf(p, w, -3.5233877e-06f);
        p = fmaf(p, w, -4.39150654e-06f);
        p = fmaf(p, w, 0.00021858087f);
        p = fmaf(p, w, -0.00125372503f);
        p = fmaf(p, w, -0.00417768164f);
        p = fmaf(p, w, 0.246640727f);
        p = fmaf(p, w, 1.50140941f);
    } else {
        w = sqrtf(w) - 3.0f;
        p = -0.000200214257f;
        p = fmaf(p, w, 0.000100950558f);
        p = fmaf(p, w, 0.00134934322f);
        p = fmaf(p, w, -0.00367342844f);
        p = fmaf(p, w, 0.00573950773f);
        p = fmaf(p, w, -0.0076224613f);
        p = fmaf(p, w, 0.00943887047f);
        p = fmaf(p, w, 1.00167406f);
        p = fmaf(p, w, 2.83297682f);
    }
    return 1.4142135623730951f * (p * x);
}

__device__ inline float normal_scalar(U2 key) {
    return bits_to_normal(tf2x32(key, 0u, 0u).a);
}

__device__ inline float uniform_scalar(U2 key) {
    uint32_t bits = tf2x32(key, 0u, 0u).a;
    return bits_to_u01(bits);
}

// ---------------------------------------------------------------------------
// Marsaglia-Tsang gamma sampler in log-space (alpha >= 1 path), JAX _gamma_one
// ---------------------------------------------------------------------------
__device__ float gamma_log_one(U2 key, float d, float c) {
    #pragma clang fp contract(off)
    float X = 0.0f, V = 1.0f, U = 2.0f;
    for (;;) {
        float x2 = X * X;
        float sq = 1.0f - 0.0331f * (x2 * x2);
        bool cont;
        if (U < sq) {
            cont = false;
        } else {
            float rhs = X * (0.5f * X) + d * ((1.0f - V) + logf(V));
            cont = (logf(U) >= rhs);
        }
        if (!cont) break;

        U2 t03 = tf2x32(key, 0u, 3u);
        U2 t14 = tf2x32(key, 1u, 4u);
        U2 t25 = tf2x32(key, 2u, 5u);
        U2 nkey; nkey.a = t03.a; nkey.b = t14.a;
        U2 xkey; xkey.a = t25.a; xkey.b = t03.b;
        U2 Ukey; Ukey.a = t14.b; Ukey.b = t25.b;
        key = nkey;

        float x, v;
        do {
            U2 s02 = tf2x32(xkey, 0u, 2u);
            U2 s13 = tf2x32(xkey, 1u, 3u);
            U2 sub; sub.a = s02.b; sub.b = s13.b;
            xkey.a = s02.a; xkey.b = s13.a;
            x = normal_scalar(sub);
            v = 1.0f + c * x;
        } while (v <= 0.0f);
        X = x;
        V = (v * v) * v;
        U = uniform_scalar(Ukey);
    }
    return logf(d) + logf(V);
}

// ---------------------------------------------------------------------------
// f32 -> bf16 (round-nearest-even), finite inputs
// ---------------------------------------------------------------------------
__device__ inline unsigned short f2bf(float f) {
    uint32_t u = __float_as_uint(f);
    uint32_t r = (u + 0x7FFFu + ((u >> 16) & 1u)) >> 16;
    return (unsigned short)r;
}

__device__ inline uint32_t pkbf2(float a, float b) {
    return (uint32_t)f2bf(a) | ((uint32_t)f2bf(b) << 16);
}

// ---------------------------------------------------------------------------
// Wood's rejection sampler, ROUND-PARALLEL (4 lanes/element, bit-exact)
// ---------------------------------------------------------------------------
__device__ void wood_w_par(int e, U2 key_a, U2 key_b, U2 ku, float xxf,
                           float ccf, float Ap, float Bm, float d, float c,
                           float* __restrict__ w_out) {
    #pragma clang fp contract(off)
    const int lane = threadIdx.x & 63;
    const int s = lane & 3;
    const int gbase = lane & ~3;
    float w0 = 0.0f, w_sel = 0.0f;
    bool done = false;
    for (int base = 0; base < 64 && !done; base += 4) {
        const int r = base + s;
        uint32_t j = (uint32_t)r * 16384u + (uint32_t)e;
        uint32_t m0 = 2u * j, m1 = 2u * j + 1u;
        U2 ka, kb;
        if (m1 < 1048576u) {
            ka.a = tf2x32(key_a, m0, m0 + 1048576u).a;
            ka.b = tf2x32(key_a, m1, m1 + 1048576u).a;
            kb.a = tf2x32(key_b, m0, m0 + 1048576u).a;
            kb.b = tf2x32(key_b, m1, m1 + 1048576u).a;
        } else {
            ka.a = tf2x32(key_a, m0 - 1048576u, m0).b;
            ka.b = tf2x32(key_a, m1 - 1048576u, m1).b;
            kb.a = tf2x32(key_b, m0 - 1048576u, m0).b;
            kb.b = tf2x32(key_b, m1 - 1048576u, m1).b;
        }
        float lga = gamma_log_one(ka, d, c);
        float lgb = gamma_log_one(kb, d, c);
        float mx = fmaxf(lga, lgb);
        float ga = expf(lga - mx), gb = expf(lgb - mx);
        float z = ga / (ga + gb);
        uint32_t ub = (j < 524288u) ? tf2x32(ku, j, j + 524288u).a
                                    : tf2x32(ku, j - 524288u, j).b;
        float u = bits_to_u01(ub);
        float w = (1.0f - Ap * z) / (1.0f - Bm * z);
        float lhs = (80.0f * w + 511.0f * logf(1.0f - xxf * w)) - ccf;
        bool acc = lhs >= logf(u);
        if (base == 0) w0 = __shfl(w, gbase, 64);
        unsigned long long m = __ballot(acc);
        unsigned nib = (unsigned)((m >> gbase) & 0xFull);
        if (nib) {
            int first = __ffs((int)nib) - 1;
            w_sel = __shfl(w, gbase + first, 64);
            done = true;
        }
    }
    if (!done) w_sel = w0;
    if (s == 0) w_out[e] = w_sel;
}

// ---------------------------------------------------------------------------
// prep3 (Path A): wood-parallel + convert_a + transpose_w + kld, grid-fused.
// Swizzle (BK=64): within each 64-k chunk, 16B-block pos p = g ^ (row&7).
//   blocks [0,256)     : Wood's w, round-parallel (64 elems/block)
//   blocks [256,4352)  : A f32 -> swizzled bf16 (4 rows/block)
//   blocks [4352,4480) : W transpose -> swizzled bf16 Wt
//   block  4480        : kld copy
// ---------------------------------------------------------------------------
__global__ __launch_bounds__(256) void prep3(
    const float* __restrict__ A, unsigned short* __restrict__ Ab,
    const float* __restrict__ Wm, unsigned short* __restrict__ Wt,
    const float* __restrict__ kld, float* __restrict__ kldo,
    U2 key_a, U2 key_b, U2 ku, float xxf, float ccf, float Ap, float Bm,
    float d, float c, float* __restrict__ wbuf) {
    __shared__ float t[64][65];
    const int b = blockIdx.x;
    if (b < 256) {
        const int wavid = threadIdx.x >> 6;
        const int e = b * 64 + wavid * 16 + ((threadIdx.x & 63) >> 2);
        wood_w_par(e, key_a, key_b, ku, xxf, ccf, Ap, Bm, d, c, wbuf);
    } else if (b < 4352) {
        const int row = (b - 256) * 4 + (threadIdx.x >> 6);
        const int lane = threadIdx.x & 63;
        const float* src = A + (size_t)row * 1024;
        unsigned short* dst = Ab + (size_t)row * 1024;
        const int rx = row & 7;
        #pragma unroll
        for (int q = 0; q < 4; ++q) {
            const int k0 = q * 256 + lane * 4;
            float4 v = *(const float4*)(src + k0);
            ushort4 w;
            w.x = f2bf(v.x); w.y = f2bf(v.y); w.z = f2bf(v.z); w.w = f2bf(v.w);
            const int kt = k0 >> 6;
            const int g = (k0 >> 3) & 7;
            const int e2 = k0 & 7;
            *(ushort4*)(dst + kt * 64 + ((g ^ rx) << 3) + e2) = w;
        }
    } else if (b < 4480) {
        const int tb = b - 4352;
        const int kb = tb & 15;
        const int nb = tb >> 4;
        const int tx = threadIdx.x & 63;
        const int ty = threadIdx.x >> 6;
        #pragma unroll
        for (int i = 0; i < 64; i += 4)
            t[i + ty][tx] = Wm[(size_t)(kb * 64 + i + ty) * 512 + nb * 64 + tx];
        __syncthreads();
        const int g = tx >> 3, e2 = tx & 7;
        #pragma unroll
        for (int i = 0; i < 64; i += 4) {
            int n = i + ty;
            int nglob = nb * 64 + n;
            int p = g ^ (nglob & 7);
            Wt[(size_t)nglob * 1024 + kb * 64 + p * 8 + e2] = f2bf(t[tx][n]);
        }
    } else {
        if (threadIdx.x == 0) kldo[0] = kld[0];
    }
}

// ---------------------------------------------------------------------------
// GEMM (Path A): pure-DMA, counted-vmcnt 2-deep pipeline (R11-verified).
// BM=128 BN=128 BK=64, 256 thr / 4 waves (2x2), wave tile 64x64 (4x4 frags).
// ---------------------------------------------------------------------------
typedef __attribute__((ext_vector_type(8))) short bf16x8;
typedef __attribute__((ext_vector_type(4))) float f32x4;

__device__ inline void gll16(const void* g, void* l) {
    __builtin_amdgcn_global_load_lds(
        (const __attribute__((address_space(1))) void*)g,
        (__attribute__((address_space(3))) void*)l, 16, 0, 0);
}

__global__ __launch_bounds__(256) void gemm_dma(
    const unsigned short* __restrict__ Ab, const unsigned short* __restrict__ Wt,
    const float* __restrict__ bias, float* __restrict__ out) {
    __shared__ __align__(16) unsigned short Asm[2][8192];
    __shared__ __align__(16) unsigned short Bsm[2][8192];
    const int tid = threadIdx.x;
    const int b = blockIdx.x;
    const int swz = (b & 7) * 64 + (b >> 3);     // XCD-chunked, bijective
    const int bm = swz >> 2;
    const int bn = swz & 3;
    const int wave = tid >> 6, lane = tid & 63;
    const int wm = wave >> 1, wn = wave & 1;
    const int lr = lane & 15, lg = lane >> 4;

    f32x4 acc[4][4] = {};

    const char* aBase = (const char*)Ab +
        (size_t)(bm * 128 + wave * 32 + (lane >> 3)) * 2048 + (lane & 7) * 16;
    const char* bBase = (const char*)Wt +
        (size_t)(bn * 128 + wave * 32 + (lane >> 3)) * 2048 + (lane & 7) * 16;

#define STAGE(ktv, buf)                                                     \
    {                                                                       \
        _Pragma("unroll")                                                   \
        for (int ii = 0; ii < 4; ++ii) {                                    \
            const int chunk = wave * 4 + ii;                                \
            gll16(aBase + (size_t)ii * 8 * 2048 + (ktv) * 128,              \
                  (void*)&Asm[buf][chunk * 512]);                           \
            gll16(bBase + (size_t)ii * 8 * 2048 + (ktv) * 128,              \
                  (void*)&Bsm[buf][chunk * 512]);                           \
        }                                                                   \
    }

    STAGE(0, 0);
    STAGE(1, 1);
    asm volatile("s_waitcnt vmcnt(8)" ::: "memory");
    __builtin_amdgcn_s_barrier();
    __builtin_amdgcn_sched_barrier(0);

    int cur = 0;
    for (int kt = 0; kt < 16; ++kt) {
        #pragma unroll
        for (int ks = 0; ks < 2; ++ks) {
            bf16x8 af[4], bfr[4];
            #pragma unroll
            for (int mi = 0; mi < 4; ++mi) {
                const int r = wm * 64 + mi * 16 + lr;
                const int p = (ks * 4 + lg) ^ (r & 7);
                af[mi] = *(const bf16x8*)&Asm[cur][r * 64 + p * 8];
            }
            #pragma unroll
            for (int ni = 0; ni < 4; ++ni) {
                const int r = wn * 64 + ni * 16 + lr;
                const int p = (ks * 4 + lg) ^ (r & 7);
                bfr[ni] = *(const bf16x8*)&Bsm[cur][r * 64 + p * 8];
            }
            #pragma unroll
            for (int mi = 0; mi < 4; ++mi)
                #pragma unroll
                for (int ni = 0; ni < 4; ++ni)
                    acc[mi][ni] = __builtin_amdgcn_mfma_f32_16x16x32_bf16(
                        af[mi], bfr[ni], acc[mi][ni], 0, 0, 0);
        }
        __builtin_amdgcn_sched_barrier(0);
        __builtin_amdgcn_s_barrier();
        if (kt + 2 < 16) {
            STAGE(kt + 2, cur);
            asm volatile("s_waitcnt vmcnt(8)" ::: "memory");
        } else {
            asm volatile("s_waitcnt vmcnt(0)" ::: "memory");
        }
        __builtin_amdgcn_s_barrier();
        __builtin_amdgcn_sched_barrier(0);
        cur ^= 1;
    }
#undef STAGE

    #pragma unroll
    for (int mi = 0; mi < 4; ++mi) {
        #pragma unroll
        for (int ni = 0; ni < 4; ++ni) {
            const int col = bn * 128 + wn * 64 + ni * 16 + lr;
            const float bcol = bias[col];
            #pragma unroll
            for (int r = 0; r < 4; ++r) {
                const int row = bm * 128 + wm * 64 + mi * 16 + lg * 4 + r;
                float x = acc[mi][ni][r] + bcol;
                float sp = fmaxf(x, 0.0f) + __logf(1.0f + __expf(-fabsf(x)));
                out[(size_t)row * 512 + col] = sp;
            }
        }
    }
}

// ---------------------------------------------------------------------------
// Path B fallback kernels
// ---------------------------------------------------------------------------
__device__ void wood_w_one(int i, U2 key_a, U2 key_b, U2 ku, float xxf,
                           float ccf, float Ap, float Bm, float d, float c,
                           float* __restrict__ w_out) {
    #pragma clang fp contract(off)
    float w_sel = 0.0f, w0 = 0.0f;
    bool found = false;
    for (int r = 0; r < 64 && !found; ++r) {
        uint32_t j = (uint32_t)r * 16384u + (uint32_t)i;
        uint32_t m0 = 2u * j, m1 = 2u * j + 1u;
        U2 ka, kb;
        if (m1 < 1048576u) {
            ka.a = tf2x32(key_a, m0, m0 + 1048576u).a;
            ka.b = tf2x32(key_a, m1, m1 + 1048576u).a;
            kb.a = tf2x32(key_b, m0, m0 + 1048576u).a;
            kb.b = tf2x32(key_b, m1, m1 + 1048576u).a;
        } else {
            ka.a = tf2x32(key_a, m0 - 1048576u, m0).b;
            ka.b = tf2x32(key_a, m1 - 1048576u, m1).b;
            kb.a = tf2x32(key_b, m0 - 1048576u, m0).b;
            kb.b = tf2x32(key_b, m1 - 1048576u, m1).b;
        }
        float lga = gamma_log_one(ka, d, c);
        float lgb = gamma_log_one(kb, d, c);
        float mx = fmaxf(lga, lgb);
        float ga = expf(lga - mx), gb = expf(lgb - mx);
        float z = ga / (ga + gb);
        uint32_t ub = (j < 524288u) ? tf2x32(ku, j, j + 524288u).a
                                    : tf2x32(ku, j - 524288u, j).b;
        float u = bits_to_u01(ub);
        float w = (1.0f - Ap * z) / (1.0f - Bm * z);
        float lhs = (80.0f * w + 511.0f * logf(1.0f - xxf * w)) - ccf;
        bool acc = lhs >= logf(u);
        if (r == 0) w0 = w;
        if (acc) { w_sel = w; found = true; }
    }
    w_out[i] = found ? w_sel : w0;
}

__global__ __launch_bounds__(256) void transpose_w(
    const float* __restrict__ Wm, unsigned short* __restrict__ Wt) {
    __shared__ float t[64][65];
    const int kb = blockIdx.x;
    const int nb = blockIdx.y;
    const int tx = threadIdx.x & 63;
    const int ty = threadIdx.x >> 6;
    #pragma unroll
    for (int i = 0; i < 64; i += 4)
        t[i + ty][tx] = Wm[(size_t)(kb * 64 + i + ty) * 512 + nb * 64 + tx];
    __syncthreads();
    const int g = tx >> 3, e = tx & 7;
    #pragma unroll
    for (int i = 0; i < 64; i += 4) {
        int n = i + ty;
        int nglob = nb * 64 + n;
        int p = g ^ (nglob & 7);
        Wt[(size_t)nglob * 1024 + kb * 64 + p * 8 + e] = f2bf(t[tx][n]);
    }
}

__global__ __launch_bounds__(256) void gemm_bf16(
    const float* __restrict__ A, const unsigned short* __restrict__ Wt,
    const float* __restrict__ bias, float* __restrict__ out) {
    __shared__ __align__(16) unsigned short Asm[128 * 64];
    __shared__ __align__(16) unsigned short Bsm[128 * 64];
    const int tid = threadIdx.x;
    const int b = blockIdx.x;
    const int swz = (b & 7) * 64 + (b >> 3);
    const int bm = swz >> 2;
    const int bn = swz & 3;
    const int wave = tid >> 6, lane = tid & 63;
    const int wm = wave >> 1, wn = wave & 1;
    const int lr = lane & 15, lg = lane >> 4;

    f32x4 acc[4][4] = {};

    const int ar = tid >> 1;
    const int ah = tid & 1;
    const float* Ap = A + (size_t)(bm * 128 + ar) * 1024 + ah * 32;
    const int arx = ar & 7;

    const char* WtB = (const char*)Wt;
    const int brow = bn * 128 + (wave * 4) * 8 + (lane >> 3);
    const int bposb = (lane & 7) * 16;

    for (int kt = 0; kt < 16; ++kt) {
        #pragma unroll
        for (int ii = 0; ii < 4; ++ii) {
            const int chunk = wave * 4 + ii;
            const void* src = WtB + (size_t)(brow + ii * 8) * 2048 + kt * 128 + bposb;
            gll16(src, (void*)&Bsm[chunk * 512]);
        }
        const float* srcA = Ap + kt * 64;
        #pragma unroll
        for (int st = 0; st < 4; ++st) {
            float4 y0 = *(const float4*)(srcA + st * 8);
            float4 y1 = *(const float4*)(srcA + st * 8 + 4);
            uint4 uv;
            uv.x = pkbf2(y0.x, y0.y);
            uv.y = pkbf2(y0.z, y0.w);
            uv.z = pkbf2(y1.x, y1.y);
            uv.w = pkbf2(y1.z, y1.w);
            const int gblk = ah * 4 + st;
            const int p = gblk ^ arx;
            *(uint4*)&Asm[ar * 64 + p * 8] = uv;
        }
        __syncthreads();

        #pragma unroll
        for (int ks = 0; ks < 2; ++ks) {
            bf16x8 af[4], bfr[4];
            #pragma unroll
            for (int mi = 0; mi < 4; ++mi) {
                const int r = wm * 64 + mi * 16 + lr;
                const int p = (ks * 4 + lg) ^ (r & 7);
                af[mi] = *(const bf16x8*)&Asm[r * 64 + p * 8];
            }
            #pragma unroll
            for (int ni = 0; ni < 4; ++ni) {
                const int r = wn * 64 + ni * 16 + lr;
                const int p = (ks * 4 + lg) ^ (r & 7);
                bfr[ni] = *(const bf16x8*)&Bsm[r * 64 + p * 8];
            }
            #pragma unroll
            for (int mi = 0; mi < 4; ++mi)
                #pragma unroll
                for (int ni = 0; ni < 4; ++ni)
                    acc[mi][ni] = __builtin_amdgcn_mfma_f32_16x16x32_bf16(
                        af[mi], bfr[ni], acc[mi][ni], 0, 0, 0);
        }
        __syncthreads();
    }

    #pragma unroll
    for (int mi = 0; mi < 4; ++mi) {
        #pragma unroll
        for (int ni = 0; ni < 4; ++ni) {
            const int col = bn * 128 + wn * 64 + ni * 16 + lr;
            const float bcol = bias[col];
            #pragma unroll
            for (int r = 0; r < 4; ++r) {
                const int row = bm * 128 + wm * 64 + mi * 16 + lg * 4 + r;
                float x = acc[mi][ni][r] + bcol;
                float sp = fmaxf(x, 0.0f) + log1pf(expf(-fabsf(x)));
                out[(size_t)row * 512 + col] = sp;
            }
        }
    }
}

__global__ __launch_bounds__(64) void compute_w_kernel(
    U2 key_a, U2 key_b, U2 ku, float xxf, float ccf, float Ap, float Bm,
    float d, float c, float* __restrict__ w_out) {
    const int i = blockIdx.x * blockDim.x + threadIdx.x;
    if (i >= 16384) return;
    wood_w_one(i, key_a, key_b, ku, xxf, ccf, Ap, Bm, d, c, w_out);
}

__global__ void copy_kld(const float* __restrict__ kld, float* __restrict__ dst) {
    if (blockIdx.x == 0 && threadIdx.x == 0) dst[0] = kld[0];
}

// ---------------------------------------------------------------------------
// finalize2: barrier-free, row-pair (r, r+8192) per wave, halved threefry.
// v-normal hashing moved BEFORE the mu-load consumption so the muraw HBM
// latency hides under ~600 cyc of threefry/erfinv VALU.
// ---------------------------------------------------------------------------
__device__ inline float wave_allreduce(float s) {
    #pragma unroll
    for (int off = 1; off < 64; off <<= 1) s += __shfl_xor(s, off);
    return s;
}

__global__ __launch_bounds__(256) void finalize2(
    const float* muraw, float* muout, float* __restrict__ rn,
    const float* __restrict__ wv, U2 kv, float* smp) {
    const int p = blockIdx.x * 4 + (threadIdx.x >> 6);   // row pair 0..8191
    const int lane = threadIdx.x & 63;
    const int r0 = p, r1 = p + 8192;
    const float* q0 = muraw + (size_t)r0 * 512;
    const float* q1 = muraw + (size_t)r1 * 512;

    // issue mu loads first...
    float4 t0 = *(const float4*)(q0 + lane * 4);
    float4 t1 = *(const float4*)(q0 + 256 + lane * 4);
    float4 t2 = *(const float4*)(q1 + lane * 4);
    float4 t3 = *(const float4*)(q1 + 256 + lane * 4);
    float wv0 = wv[r0], wv1 = wv[r1];

    // ...then do the load-independent hash work while they fly
    float v0[8], v1[8];
    #pragma unroll
    for (int j = 0; j < 8; ++j) {
        const int c = (j < 4) ? (lane * 4 + j) : (256 + lane * 4 + (j - 4));
        uint32_t idx = (uint32_t)p * 512u + (uint32_t)c;
        U2 h = tf2x32(kv, idx, idx + 4194304u);
        v0[j] = bits_to_normal_fast(h.a);
        v1[j] = bits_to_normal_fast(h.b);
    }

    float m0[8], m1[8];
    m0[0] = t0.x; m0[1] = t0.y; m0[2] = t0.z; m0[3] = t0.w;
    m0[4] = t1.x; m0[5] = t1.y; m0[6] = t1.z; m0[7] = t1.w;
    m1[0] = t2.x; m1[1] = t2.y; m1[2] = t2.z; m1[3] = t2.w;
    m1[4] = t3.x; m1[5] = t3.y; m1[6] = t3.z; m1[7] = t3.w;

    float ss0 = 0.0f, ss1 = 0.0f;
    #pragma unroll
    for (int j = 0; j < 8; ++j) { ss0 += m0[j] * m0[j]; ss1 += m1[j] * m1[j]; }
    float n0 = sqrtf(wave_allreduce(ss0));
    float n1 = sqrtf(wave_allreduce(ss1));
    if (lane == 0) {
        float d0 = n0 - 1.0f, d1 = n1 - 1.0f;
        rn[r0] = d0 * d0;
        rn[r1] = d1 * d1;
    }
    float in0 = 1.0f / n0, in1 = 1.0f / n1;
    #pragma unroll
    for (int j = 0; j < 8; ++j) { m0[j] *= in0; m1[j] *= in1; }

    float p0 = 0.0f, p1 = 0.0f;
    #pragma unroll
    for (int j = 0; j < 8; ++j) { p0 += m0[j] * v0[j]; p1 += m1[j] * v1[j]; }
    p0 = wave_allreduce(p0);
    p1 = wave_allreduce(p1);

    float o0[8], o1[8];
    float s0 = 0.0f, s1 = 0.0f;
    #pragma unroll
    for (int j = 0; j < 8; ++j) {
        o0[j] = v0[j] - m0[j] * p0; s0 += o0[j] * o0[j];
        o1[j] = v1[j] - m1[j] * p1; s1 += o1[j] * o1[j];
    }
    float f0, f1;
    {
        float on0 = sqrtf(wave_allreduce(s0));
        float on1 = sqrtf(wave_allreduce(s1));
        f0 = sqrtf(1.0f - wv0 * wv0) / on0;
        f1 = sqrtf(1.0f - wv1 * wv1) / on1;
    }

    float* pm0 = muout + (size_t)r0 * 512;
    float* pm1 = muout + (size_t)r1 * 512;
    float* op0 = smp + (size_t)r0 * 512;
    float* op1 = smp + (size_t)r1 * 512;
    float4 wvec;
    wvec.x = o0[0] * f0 + m0[0] * wv0; wvec.y = o0[1] * f0 + m0[1] * wv0;
    wvec.z = o0[2] * f0 + m0[2] * wv0; wvec.w = o0[3] * f0 + m0[3] * wv0;
    *(float4*)(op0 + lane * 4) = wvec;
    wvec.x = o0[4] * f0 + m0[4] * wv0; wvec.y = o0[5] * f0 + m0[5] * wv0;
    wvec.z = o0[6] * f0 + m0[6] * wv0; wvec.w = o0[7] * f0 + m0[7] * wv0;
    *(float4*)(op0 + 256 + lane * 4) = wvec;
    wvec.x = o1[0] * f1 + m1[0] * wv1; wvec.y = o1[1] * f1 + m1[1] * wv1;
    wvec.z = o1[2] * f1 + m1[2] * wv1; wvec.w = o1[3] * f1 + m1[3] * wv1;
    *(float4*)(op1 + lane * 4) = wvec;
    wvec.x = o1[4] * f1 + m1[4] * wv1; wvec.y = o1[5] * f1 + m1[5] * wv1;
    wvec.z = o1[6] * f1 + m1[6] * wv1; wvec.w = o1[7] * f1 + m1[7] * wv1;
    *(float4*)(op1 + 256 + lane * 4) = wvec;

    wvec.x = m0[0]; wvec.y = m0[1]; wvec.z = m0[2]; wvec.w = m0[3];
    *(float4*)(pm0 + lane * 4) = wvec;
    wvec.x = m0[4]; wvec.y = m0[5]; wvec.z = m0[6]; wvec.w = m0[7];
    *(float4*)(pm0 + 256 + lane * 4) = wvec;
    wvec.x = m1[0]; wvec.y = m1[1]; wvec.z = m1[2]; wvec.w = m1[3];
    *(float4*)(pm1 + lane * 4) = wvec;
    wvec.x = m1[4]; wvec.y = m1[5]; wvec.z = m1[6]; wvec.w = m1[7];
    *(float4*)(pm1 + 256 + lane * 4) = wvec;
}

// ---------------------------------------------------------------------------
extern "C" void kernel_launch(void* const* d_in, const int* in_sizes, int n_in,
                              void* d_out, int out_size, void* d_ws, size_t ws_size,
                              hipStream_t stream) {
    const float* A    = (const float*)d_in[0];   // [16384,1024]
    const float* Wm   = (const float*)d_in[1];   // [1024,512]
    const float* bias = (const float*)d_in[2];   // [512]
    const float* kld  = (const float*)d_in[3];   // [1]

    float* out = (float*)d_out;
    float* mu   = out;                       // 16384*512
    float* rn   = out + 8388608;             // 16384
    float* kldo = out + 8388608 + 16384;     // 1
    float* smp  = kldo + 1;                  // 16384*512
    float* wbuf = (float*)d_ws;              // 16384 floats scratch

    // ---- host-side key derivation (JAX threefry), key = jax.random.key(42)
    U2 root; root.a = 0u; root.b = 42u;
    U2 t02 = tf2x32(root, 0u, 2u), t13 = tf2x32(root, 1u, 3u);
    U2 kw; kw.a = t02.a; kw.b = t13.a;
    U2 kv; kv.a = t02.b; kv.b = t13.b;
    U2 s02 = tf2x32(kw, 0u, 2u), s13 = tf2x32(kw, 1u, 3u);
    U2 kz; kz.a = s02.a; kz.b = s13.a;
    U2 ku; ku.a = s02.b; ku.b = s13.b;
    U2 b02 = tf2x32(kz, 0u, 2u), b13 = tf2x32(kz, 1u, 3u);
    U2 key_a; key_a.a = b02.a; key_a.b = b13.a;
    U2 key_b; key_b.a = b02.b; key_b.b = b13.b;

    // ---- Wood's sampler constants
    const double kappa = 80.0, dim = 511.0;
    double bb = dim / (sqrt(4.0 * kappa * kappa + dim * dim) + 2.0 * kappa);
    double xxd = (1.0 - bb) / (1.0 + bb);
    double ccd = kappa * xxd + dim * log(1.0 - xxd * xxd);
    float xxf = (float)xxd, ccf = (float)ccd;
    float Apc = (float)(1.0 + bb), Bmc = (float)(1.0 - bb);
    float one3 = 1.0f / 3.0f;
    float dml = 255.5f - one3;
    float cml = one3 / sqrtf(dml);

    const bool bigws = ws_size >= (size_t)(65536 + 1048576);
    if (bigws) {
        unsigned short* Ab = (unsigned short*)d_out;
        unsigned short* Wt = (unsigned short*)((char*)d_ws + 65536);
        float* muraw = smp;
        prep3<<<4481, 256, 0, stream>>>(A, Ab, Wm, Wt, kld, kldo,
                                        key_a, key_b, ku, xxf, ccf, Apc, Bmc,
                                        dml, cml, wbuf);
        gemm_dma<<<512, 256, 0, stream>>>(Ab, Wt, bias, muraw);
        finalize2<<<2048, 256, 0, stream>>>(muraw, mu, rn, wbuf, kv, smp);
    } else {
        unsigned short* Wt = (unsigned short*)((char*)d_out + 33619984);
        compute_w_kernel<<<256, 64, 0, stream>>>(key_a, key_b, ku, xxf, ccf,
                                                 Apc, Bmc, dml, cml, wbuf);
        transpose_w<<<dim3(16, 8), 256, 0, stream>>>(Wm, Wt);
        gemm_bf16<<<512, 256, 0, stream>>>(A, Wt, bias, mu);
        finalize2<<<2048, 256, 0, stream>>>(mu, mu, rn, wbuf, kv, smp);
        copy_kld<<<1, 64, 0, stream>>>(kld, kldo);
    }
}